// Round 9
// baseline (167.225 us; speedup 1.0000x reference)
//
#include <hip/hip_runtime.h>
#include <cstdint>
#include <cstddef>

#define BB 4
#define LL 1024
#define HH 768
#define AA 12
#define EE 32
#define PP 992           // EE*(EE-1)
#define PPAD 1024
#define NROW (BB*PPAD)   // 4096
#define NN (BB*PP)       // 3968
#define RR 97
#define RP 112
#define GS2 16           // logits K-slices (K=3072 each)

typedef __attribute__((ext_vector_type(8))) _Float16 half8;
typedef __attribute__((ext_vector_type(4))) _Float16 half4v;
typedef __attribute__((ext_vector_type(2))) _Float16 half2v;
typedef __attribute__((ext_vector_type(4))) float floatx4;

union H8u { half8 v8; half2v v2[4]; };

#define WAITVM(N) asm volatile("s_waitcnt vmcnt(" #N ")" ::: "memory")

__device__ __forceinline__ void gl_lds16(const void* g, void* l) {
    __builtin_amdgcn_global_load_lds(
        (const __attribute__((address_space(1))) unsigned int*)g,
        (__attribute__((address_space(3))) unsigned int*)l, 16, 0, 0);
}

// raw barrier (manual counted vmcnt waits around it; no auto drain)
__device__ __forceinline__ void barrier_raw() {
    asm volatile("" ::: "memory");
    __builtin_amdgcn_s_barrier();
    __builtin_amdgcn_sched_barrier(0);
    asm volatile("" ::: "memory");
}

__device__ __forceinline__ int xswz96(int bid) {  // 768 blocks -> 8 XCD chunks of 96
    return (bid & 7) * 96 + (bid >> 3);
}

__device__ __forceinline__ void pair_decode(int p, int& i0, int& i1) {
    i0 = p / 31;
    int r = p - i0 * 31;
    i1 = r + (r >= i0 ? 1 : 0);
}

__device__ __forceinline__ float fast_tanh(float x) {
    float ax = fabsf(x);
    float t = __builtin_amdgcn_exp2f(ax * -2.885390082f);   // exp(-2|x|)
    float r = (1.f - t) * __builtin_amdgcn_rcpf(1.f + t);
    return copysignf(r, x);
}

// ---------------------------------------------------------------------------
// stage0 (merged independent sections):
//  [0,1536)    Wc repack via LDS (coalesced): one 32-row k-step per block
//  [1536,2112) Wh2/Wt2 -> frag layout (48 col-tiles)
//  [2112,3648) hid f32 -> f16 row-major
//  [3648,4160) ent_attn gather (be, quarter)
//  [4160,4256) Fht[mat,b,e,:] = ((hid[hd]+hid[tl])/2) @ W1 + bias (f32 GEMM,
//              gathers hid rows directly -- no ent_feat buffer)
// ---------------------------------------------------------------------------
__global__ __launch_bounds__(256) void k_stage0(
        const float* __restrict__ hid, const float* __restrict__ att,
        const int* __restrict__ head, const int* __restrict__ tail,
        const float* __restrict__ Wh, const float* __restrict__ bh,
        const float* __restrict__ Wt, const float* __restrict__ bt,
        const float* __restrict__ Wc,
        _Float16* __restrict__ hidb, _Float16* __restrict__ Whf,
        _Float16* __restrict__ Wtf, _Float16* __restrict__ Wcp,
        float* __restrict__ ent_attn, float* __restrict__ Fht) {
    __shared__ float ldw[32][101];   // Wc staging (pad 101 spreads banks)
    __shared__ float fs[EE][68];
    __shared__ float ws_[64][68];
    __shared__ int hds[EE], tls[EE];
    int bid = blockIdx.x, tid = threadIdx.x;
    if (bid < 1536) {
        int ksg = bid;
        int w = tid >> 6, lane = tid & 63;
        const float* src = Wc + (size_t)ksg * 32 * RR;
        #pragma unroll
        for (int rr = 0; rr < 8; ++rr) {
            int row = w * 8 + rr;
            ldw[row][lane] = src[(size_t)row * RR + lane];
            if (lane < 33) ldw[row][64 + lane] = src[(size_t)row * RR + 64 + lane];
        }
        __syncthreads();
        #pragma unroll
        for (int j = 0; j < 2; ++j) {
            int f = tid + j * 256;
            int rt = f >> 6, lf = f & 63;
            int c = rt * 16 + (lf & 15);
            int kb = (lf >> 4) * 8;
            _Float16 v[8];
            #pragma unroll
            for (int e = 0; e < 8; ++e)
                v[e] = (c < RR) ? (_Float16)ldw[kb + e][c] : (_Float16)0.f;
            *(half8*)(Wcp + ((size_t)ksg * 512 + f) * 8) = *(const half8*)v;
        }
    } else if (bid < 2112) {
        int which = (bid < 1824) ? 0 : 1;
        const float* src = (which ? Wt : Wh) + (size_t)HH * HH;
        _Float16* dst = which ? Wtf : Whf;
        int idx = (bid - (which ? 1824 : 1536)) * 256 + tid;   // 73728 = 24*48*64
        int lane = idx & 63, f = idx >> 6;
        int ct = f % 48, ks = f / 48;
        int c = ct * 16 + (lane & 15);
        int kb = ks * 32 + (lane >> 4) * 8;
        _Float16 v[8];
        #pragma unroll
        for (int e = 0; e < 8; ++e)
            v[e] = (_Float16)src[(size_t)(kb + e) * HH + c];
        *(half8*)(dst + (size_t)idx * 8) = *(const half8*)v;
    } else if (bid < 3648) {
        int idx = (bid - 2112) * 256 + tid;
        const float* s = hid + (size_t)idx * 8;
        float4 a = *(const float4*)s;
        float4 b = *(const float4*)(s + 4);
        half8 v = { (_Float16)a.x, (_Float16)a.y, (_Float16)a.z, (_Float16)a.w,
                    (_Float16)b.x, (_Float16)b.y, (_Float16)b.z, (_Float16)b.w };
        *(half8*)(hidb + (size_t)idx * 8) = v;
    } else if (bid < 4160) {
        int q = bid - 3648;                    // 512: (be, quarter)
        int be = q >> 2, qt = q & 3;
        int b = be >> 5;
        int hd = head[be], tl = tail[be];
        const float* abase = att + (size_t)b * AA * LL * LL;
        int ll = qt * 256 + tid;
        float s = 0.f;
        #pragma unroll
        for (int a = 0; a < AA; ++a) {
            const float* ar = abase + (size_t)a * LL * LL;
            s += ar[(size_t)hd * LL + ll] + ar[(size_t)tl * LL + ll];
        }
        ent_attn[(size_t)be * LL + ll] = s * (0.5f / AA);
    } else {
        int q = bid - 4160;                    // 96: (mat,b,ct)
        int ct = q % 12, b = (q / 12) % BB, mat = q / 48;
        const float* W    = mat ? Wt : Wh;     // rows [0,768) = W1 half
        const float* bias = mat ? bt : bh;
        if (tid < EE) {
            hds[tid] = head[b * EE + tid];
            tls[tid] = tail[b * EE + tid];
        }
        __syncthreads();
        int e = tid >> 3, cg = tid & 7;
        float acc[8] = {};
        for (int k0 = 0; k0 < HH; k0 += 64) {
            __syncthreads();
            #pragma unroll
            for (int it = 0; it < 2; ++it) {
                int idx = tid + it * 256;
                int ee = idx >> 4, kk = (idx & 15) * 4;
                float4 a = *(const float4*)(hid + ((size_t)b * LL + hds[ee]) * HH + k0 + kk);
                float4 c = *(const float4*)(hid + ((size_t)b * LL + tls[ee]) * HH + k0 + kk);
                float4 m = { 0.5f * (a.x + c.x), 0.5f * (a.y + c.y),
                             0.5f * (a.z + c.z), 0.5f * (a.w + c.w) };
                *(float4*)(&fs[ee][kk]) = m;
            }
            #pragma unroll
            for (int it = 0; it < 4; ++it) {
                int idx = tid + it * 256;
                int kk = idx >> 4, cc = (idx & 15) * 4;
                *(float4*)(&ws_[kk][cc]) =
                    *(const float4*)(W + (size_t)(k0 + kk) * HH + ct * 64 + cc);
            }
            __syncthreads();
            #pragma unroll
            for (int kk = 0; kk < 64; ++kk) {
                float f = fs[e][kk];
                float4 w0 = *(const float4*)(&ws_[kk][cg * 8]);
                float4 w1 = *(const float4*)(&ws_[kk][cg * 8 + 4]);
                acc[0] += f * w0.x; acc[1] += f * w0.y; acc[2] += f * w0.z; acc[3] += f * w0.w;
                acc[4] += f * w1.x; acc[5] += f * w1.y; acc[6] += f * w1.z; acc[7] += f * w1.w;
            }
        }
        int cbase = ct * 64 + cg * 8;
        float* dst = Fht + (((size_t)mat * BB + b) * EE + e) * HH + cbase;
        #pragma unroll
        for (int j = 0; j < 8; ++j) dst[j] = acc[j] + bias[cbase + j];
    }
}

// ---------------------------------------------------------------------------
// stage1: pairw only. ONE WAVE PER ROW, no LDS/barriers (4 rows/block).
// ---------------------------------------------------------------------------
__global__ __launch_bounds__(256) void k_stage1(
        const float* __restrict__ ent_attn, const float* __restrict__ am,
        _Float16* __restrict__ pairw) {
    int tid = threadIdx.x;
    int lane = tid & 63, w = tid >> 6;
    int prow = blockIdx.x * 4 + w;
    int b = prow >> 10, p = prow & 1023;
    _Float16* dst = pairw + (size_t)prow * LL;
    if (p >= PP) {
        #pragma unroll
        for (int c = 0; c < 4; ++c) {
            half4v z = {};
            *(half4v*)(dst + c * 256 + lane * 4) = z;
        }
        return;
    }
    int i0, i1; pair_decode(p, i0, i1);
    const float* e0  = ent_attn + ((size_t)b * EE + i0) * LL;
    const float* e1  = ent_attn + ((size_t)b * EE + i1) * LL;
    const float* amr = am + (size_t)b * LL;
    float wv[16];
    float s = 0.f;
    #pragma unroll
    for (int c = 0; c < 4; ++c) {
        int o = c * 256 + lane * 4;
        float4 a = *(const float4*)(e0 + o);
        float4 d = *(const float4*)(e1 + o);
        float4 m = *(const float4*)(amr + o);
        wv[c*4+0] = a.x * d.x * m.x; wv[c*4+1] = a.y * d.y * m.y;
        wv[c*4+2] = a.z * d.z * m.z; wv[c*4+3] = a.w * d.w * m.w;
        s += wv[c*4+0] + wv[c*4+1] + wv[c*4+2] + wv[c*4+3];
    }
    #pragma unroll
    for (int off = 32; off > 0; off >>= 1) s += __shfl_down(s, off, 64);
    float tot = __shfl(s, 0, 64);
    float inv = 1.0f / (tot + 1e-20f);
    #pragma unroll
    for (int c = 0; c < 4; ++c) {
        half4v o4 = { (_Float16)(wv[c*4+0] * inv), (_Float16)(wv[c*4+1] * inv),
                      (_Float16)(wv[c*4+2] * inv), (_Float16)(wv[c*4+3] * inv) };
        *(half4v*)(dst + c * 256 + lane * 4) = o4;
    }
}

// ---------------------------------------------------------------------------
// vgemm: Vh = hidb@Wh2, Vt = hidb@Wt2 (r6/r8 proven: depth-2, 4-buffer,
// one barrier/step). Output scattered into proj-B fragment layout.
// ---------------------------------------------------------------------------
__global__ __launch_bounds__(128) void k_vgemm(
        const _Float16* __restrict__ hidb,
        const _Float16* __restrict__ Whf, const _Float16* __restrict__ Wtf,
        _Float16* __restrict__ Vhf, _Float16* __restrict__ Vtf) {
    int bid = xswz96(blockIdx.x);
    int cb = bid >> 6, mI = bid & 63;
    int ct0 = cb * 4;
    __shared__ __align__(16) _Float16 Bs[4][4096];
    int tid = threadIdx.x, lane = tid & 63, wid = tid >> 6;
    int r0 = wid * 32 + (lane & 15);
    int kg8 = (lane >> 4) * 8;

    const _Float16* A0 = hidb + (size_t)(mI * 64 + r0) * HH + kg8;
    const _Float16* A1 = A0 + 16 * HH;
    const char* WhB = (const char*)Whf + (size_t)ct0 * 1024;
    const char* WtB = (const char*)Wtf + (size_t)ct0 * 1024;
    char* LB = (char*)&Bs[0][0];
    int lo = wid * 2048 + lane * 16;
    int ld = wid * 2048;

    #pragma unroll
    for (int j = 0; j < 2; ++j) {
        gl_lds16(WhB + j * 1024 + lo, LB + j * 1024 + ld);
        gl_lds16(WtB + j * 1024 + lo, LB + 4096 + j * 1024 + ld);
    }
    half8 a0c = *(const half8*)A0;
    half8 a1c = *(const half8*)A1;
    {
        const char* hs = WhB + 49152;   // step 1: +48*1024
        const char* ts = WtB + 49152;
        #pragma unroll
        for (int j = 0; j < 2; ++j) {
            gl_lds16(hs + j * 1024 + lo, LB + 8192 + j * 1024 + ld);
            gl_lds16(ts + j * 1024 + lo, LB + 8192 + 4096 + j * 1024 + ld);
        }
    }
    floatx4 aH[2][4] = {}, aT[2][4] = {};
    half8 a0n = a0c, a1n = a1c;
    for (int ks = 0; ks < 24; ++ks) {
        int buf = ks & 3;
        if (ks < 23) {
            a0n = *(const half8*)(A0 + (ks + 1) * 32);
            a1n = *(const half8*)(A1 + (ks + 1) * 32);
        }
        if (ks < 22) {
            const char* hs = WhB + (size_t)(ks + 2) * 49152;
            const char* ts = WtB + (size_t)(ks + 2) * 49152;
            char* lb = LB + ((ks + 2) & 3) * 8192;
            #pragma unroll
            for (int j = 0; j < 2; ++j) {
                gl_lds16(hs + j * 1024 + lo, lb + j * 1024 + ld);
                gl_lds16(ts + j * 1024 + lo, lb + 4096 + j * 1024 + ld);
            }
            WAITVM(12);
        } else if (ks == 22) { WAITVM(8); } else { WAITVM(2); }
        barrier_raw();
        const half8* bp = (const half8*)(LB + buf * 8192) + lane;
        __builtin_amdgcn_s_setprio(1);
        #pragma unroll
        for (int ct = 0; ct < 4; ++ct) {
            half8 bvh = bp[ct * 64];
            half8 bvt = bp[256 + ct * 64];
            aH[0][ct] = __builtin_amdgcn_mfma_f32_16x16x32_f16(a0c, bvh, aH[0][ct], 0, 0, 0);
            aH[1][ct] = __builtin_amdgcn_mfma_f32_16x16x32_f16(a1c, bvh, aH[1][ct], 0, 0, 0);
            aT[0][ct] = __builtin_amdgcn_mfma_f32_16x16x32_f16(a0c, bvt, aT[0][ct], 0, 0, 0);
            aT[1][ct] = __builtin_amdgcn_mfma_f32_16x16x32_f16(a1c, bvt, aT[1][ct], 0, 0, 0);
        }
        __builtin_amdgcn_s_setprio(0);
        a0c = a0n; a1c = a1n;
    }
    int b = mI >> 4;
    int kspB = (mI & 15) * 2 + wid;
    int u = lane >> 4, rb = lane & 15;
    int estart = (u & 1) * 4;
    size_t bofs = (size_t)b * 786432;
    #pragma unroll
    for (int rs = 0; rs < 2; ++rs) {
        int laneL = (rs * 2 + (u >> 1)) * 16 + rb;
        #pragma unroll
        for (int ct = 0; ct < 4; ++ct) {
            size_t base = bofs + ((size_t)(kspB * 48 + ct0 + ct) * 64 + laneL) * 8 + estart;
            half4v hv = { (_Float16)aH[rs][ct][0], (_Float16)aH[rs][ct][1],
                          (_Float16)aH[rs][ct][2], (_Float16)aH[rs][ct][3] };
            half4v tv = { (_Float16)aT[rs][ct][0], (_Float16)aT[rs][ct][1],
                          (_Float16)aT[rs][ct][2], (_Float16)aT[rs][ct][3] };
            *(half4v*)(Vhf + base) = hv;
            *(half4v*)(Vtf + base) = tv;
        }
    }
}

// ---------------------------------------------------------------------------
// proj: h = tanh(Fh[i0] + pairw@Vh), t = tanh(Ft[i1] + pairw@Vt).
// Outputs written in logits tile layout hb2/tb2[c8][4096][8].
// ---------------------------------------------------------------------------
__global__ __launch_bounds__(128) void k_proj_mfma(
        const _Float16* __restrict__ pairw,
        const _Float16* __restrict__ Vhf, const _Float16* __restrict__ Vtf,
        const float* __restrict__ Fht,
        _Float16* __restrict__ hb2, _Float16* __restrict__ tb2) {
    int bid = xswz96(blockIdx.x);
    int bc = bid >> 4, mI = bid & 15;       // bc = b*12+cb
    int b = bc / 12, cb = bc - b * 12;
    int ct0 = cb * 4;
    __shared__ __align__(16) _Float16 Bs[4][4096];
    int tid = threadIdx.x, lane = tid & 63, wid = tid >> 6;
    int r0 = wid * 32 + (lane & 15);
    int kg8 = (lane >> 4) * 8;

    const _Float16* A0 = pairw + (size_t)(b * PPAD + mI * 64 + r0) * LL + kg8;
    const _Float16* A1 = A0 + 16 * LL;
    const char* VhB = (const char*)(Vhf + (size_t)b * 786432) + (size_t)ct0 * 1024;
    const char* VtB = (const char*)(Vtf + (size_t)b * 786432) + (size_t)ct0 * 1024;
    char* LB = (char*)&Bs[0][0];
    int lo = wid * 2048 + lane * 16;
    int ld = wid * 2048;

    #pragma unroll
    for (int j = 0; j < 2; ++j) {
        gl_lds16(VhB + j * 1024 + lo, LB + j * 1024 + ld);
        gl_lds16(VtB + j * 1024 + lo, LB + 4096 + j * 1024 + ld);
    }
    half8 a0c = *(const half8*)A0;
    half8 a1c = *(const half8*)A1;
    {
        const char* hs = VhB + 49152;
        const char* ts = VtB + 49152;
        #pragma unroll
        for (int j = 0; j < 2; ++j) {
            gl_lds16(hs + j * 1024 + lo, LB + 8192 + j * 1024 + ld);
            gl_lds16(ts + j * 1024 + lo, LB + 8192 + 4096 + j * 1024 + ld);
        }
    }
    floatx4 aH[2][4] = {}, aT4[2][4] = {};
    half8 a0n = a0c, a1n = a1c;
    for (int ks = 0; ks < 32; ++ks) {
        int buf = ks & 3;
        if (ks < 31) {
            a0n = *(const half8*)(A0 + (ks + 1) * 32);
            a1n = *(const half8*)(A1 + (ks + 1) * 32);
        }
        if (ks < 30) {
            const char* hs = VhB + (size_t)(ks + 2) * 49152;
            const char* ts = VtB + (size_t)(ks + 2) * 49152;
            char* lb = LB + ((ks + 2) & 3) * 8192;
            #pragma unroll
            for (int j = 0; j < 2; ++j) {
                gl_lds16(hs + j * 1024 + lo, lb + j * 1024 + ld);
                gl_lds16(ts + j * 1024 + lo, lb + 4096 + j * 1024 + ld);
            }
            WAITVM(12);
        } else if (ks == 30) { WAITVM(8); } else { WAITVM(2); }
        barrier_raw();
        const half8* bp = (const half8*)(LB + buf * 8192) + lane;
        __builtin_amdgcn_s_setprio(1);
        #pragma unroll
        for (int ct = 0; ct < 4; ++ct) {
            half8 bvh = bp[ct * 64];
            half8 bvt = bp[256 + ct * 64];
            aH[0][ct]  = __builtin_amdgcn_mfma_f32_16x16x32_f16(a0c, bvh, aH[0][ct], 0, 0, 0);
            aH[1][ct]  = __builtin_amdgcn_mfma_f32_16x16x32_f16(a1c, bvh, aH[1][ct], 0, 0, 0);
            aT4[0][ct] = __builtin_amdgcn_mfma_f32_16x16x32_f16(a0c, bvt, aT4[0][ct], 0, 0, 0);
            aT4[1][ct] = __builtin_amdgcn_mfma_f32_16x16x32_f16(a1c, bvt, aT4[1][ct], 0, 0, 0);
        }
        __builtin_amdgcn_s_setprio(0);
        a0c = a0n; a1c = a1n;
    }
    const float* FhB = Fht + (size_t)b * EE * HH;
    const float* FtB = Fht + (size_t)(BB + b) * EE * HH;
    int u = lane >> 4, rb = lane & 15;
    #pragma unroll
    for (int rs = 0; rs < 2; ++rs) {
        int pb = mI * 64 + wid * 32 + rs * 16 + u * 4;
        int i0a[4], i1a[4];
        #pragma unroll
        for (int q = 0; q < 4; ++q) {
            int p = pb + q;
            if (p < PP) pair_decode(p, i0a[q], i1a[q]);
            else { i0a[q] = -1; i1a[q] = -1; }
        }
        #pragma unroll
        for (int ct = 0; ct < 4; ++ct) {
            int c = (ct0 + ct) * 16 + rb;
            int c8 = c >> 3, ce = c & 7;
            #pragma unroll
            for (int q = 0; q < 4; ++q) {
                size_t row = (size_t)b * PPAD + pb + q;
                _Float16 hv = (_Float16)0.f, tv = (_Float16)0.f;
                if (i0a[q] >= 0) {
                    hv = (_Float16)fast_tanh(aH[rs][ct][q]  + FhB[(size_t)i0a[q] * HH + c]);
                    tv = (_Float16)fast_tanh(aT4[rs][ct][q] + FtB[(size_t)i1a[q] * HH + c]);
                }
                hb2[((size_t)c8 * NROW + row) * 8 + ce] = hv;
                tb2[((size_t)c8 * NROW + row) * 8 + ce] = tv;
            }
        }
    }
}

// ---------------------------------------------------------------------------
// logits: 512 blocks = 2/CU, 4 waves x 32 rows, 16 K-slices of 3072.
// h/t tiles now staged via gl_lds16 from tiled hb2/tb2 (fully coalesced).
// Depth-2, 4-buffer, 1 barrier/step, counted vmcnt(4).
// ---------------------------------------------------------------------------
__global__ __launch_bounds__(256) void k_logits_mfma(
        const _Float16* __restrict__ hb2, const _Float16* __restrict__ tb2,
        const _Float16* __restrict__ Wcp, _Float16* __restrict__ part) {
    int bid = blockIdx.x;
    int gs = (bid & 7) * 2 + ((bid >> 3) & 1);   // K-slice 0..15
    int nb = bid >> 4;                            // row-tile 0..31
    int n0 = nb * 128;
    int g0 = (3 * gs) >> 2;                       // first g touched
    int hch0 = gs * 6;                            // h chunk base (col/8)
    int tch0 = g0 * 8;                            // t chunk base
    __shared__ __align__(16) _Float16 hT[6][128][8];    // 12 KB
    __shared__ __align__(16) _Float16 tT[16][128][8];   // 32 KB
    __shared__ __align__(16) _Float16 Bs[4][4096];      // 32 KB
    int tid = threadIdx.x, lane = tid & 63, wid = tid >> 6;

    // coalesced tile staging: each (chunk, half) is 64 rows x 16B contiguous
    for (int hc = wid; hc < 12; hc += 4) {
        int ch = hc >> 1, half = hc & 1;
        const char* src = (const char*)(hb2 +
            ((size_t)(hch0 + ch) * NROW + n0 + half * 64) * 8) + lane * 16;
        gl_lds16(src, (char*)&hT[ch][half * 64][0]);
    }
    int nchT = 96 - tch0; if (nchT > 16) nchT = 16;   // slice 15 has 8
    for (int hc = wid; hc < 32; hc += 4) {
        int ch = hc >> 1, half = hc & 1;
        if (ch < nchT) {
            const char* src = (const char*)(tb2 +
                ((size_t)(tch0 + ch) * NROW + n0 + half * 64) * 8) + lane * 16;
            gl_lds16(src, (char*)&tT[ch][half * 64][0]);
        }
    }
    __syncthreads();   // full drain once; tiles visible

    const char* WcB = (const char*)Wcp + (size_t)gs * 96 * 8192;
    char* LB = (char*)&Bs[0][0];
    int lo = wid * 2048 + lane * 16;
    int ld = wid * 2048;
    #pragma unroll
    for (int s = 0; s < 2; ++s) {
        const char* sp = WcB + (size_t)s * 8192;
        char* lb = LB + s * 8192;
        gl_lds16(sp + lo, lb + ld);
        gl_lds16(sp + 1024 + lo, lb + 1024 + ld);
    }
    int r0 = wid * 32 + (lane & 15);
    int kgrp = lane >> 4;
    int hcol0 = gs * 48, tcol0 = g0 * 64;
    floatx4 acc[2][7] = {};

    for (int ks = 0; ks < 96; ++ks) {
        int buf = ks & 3;
        int ksg = gs * 96 + ks;
        int g = ksg >> 7;
        int kin = ksg & 127;
        int i = kin >> 1, jh = kin & 1;
        int hloc = g * 64 + i - hcol0;                    // in [0,48)
        int chT = ((g * 64 + jh * 32 - tcol0) >> 3) + kgrp;
        _Float16 h0 = hT[hloc >> 3][r0][hloc & 7];
        _Float16 h1 = hT[hloc >> 3][r0 + 16][hloc & 7];
        H8u t0u, t1u, a0, a1;
        t0u.v8 = *(const half8*)&tT[chT][r0][0];
        t1u.v8 = *(const half8*)&tT[chT][r0 + 16][0];
        half2v h02 = { h0, h0 }, h12 = { h1, h1 };
        #pragma unroll
        for (int q = 0; q < 4; ++q) {
            a0.v2[q] = h02 * t0u.v2[q];
            a1.v2[q] = h12 * t1u.v2[q];
        }
        if (ks < 94) {
            const char* sp = WcB + (size_t)(ks + 2) * 8192;
            char* lb = LB + ((ks + 2) & 3) * 8192;
            gl_lds16(sp + lo, lb + ld);
            gl_lds16(sp + 1024 + lo, lb + 1024 + ld);
            WAITVM(4);
        } else if (ks == 94) { WAITVM(2); } else { WAITVM(0); }
        barrier_raw();
        const half8* bp = (const half8*)(LB + buf * 8192) + lane;
        __builtin_amdgcn_s_setprio(1);
        #pragma unroll
        for (int rt = 0; rt < 7; ++rt) {
            half8 bv = bp[rt * 64];
            acc[0][rt] = __builtin_amdgcn_mfma_f32_16x16x32_f16(a0.v8, bv, acc[0][rt], 0, 0, 0);
            acc[1][rt] = __builtin_amdgcn_mfma_f32_16x16x32_f16(a1.v8, bv, acc[1][rt], 0, 0, 0);
        }
        __builtin_amdgcn_s_setprio(0);
    }
    int rb = lane & 15, u = lane >> 4;
    #pragma unroll
    for (int rs = 0; rs < 2; ++rs) {
        int nbase = n0 + wid * 32 + rs * 16 + u * 4;
        #pragma unroll
        for (int rt = 0; rt < 7; ++rt)
            #pragma unroll
            for (int q = 0; q < 4; ++q)
                part[((size_t)gs * NROW + nbase + q) * RP + rt * 16 + rb] =
                    (_Float16)acc[rs][rt][q];
    }
}

// ---------------------------------------------------------------------------
// reduce: logits[n,r] = bc[r] + sum_gs part[gs, rowp(n), r]
// ---------------------------------------------------------------------------
__global__ __launch_bounds__(256) void k_reduce(
        const _Float16* __restrict__ part, const float* __restrict__ bc,
        float* __restrict__ out) {
    int idx = blockIdx.x * 256 + threadIdx.x;
    if (idx >= NN * RR) return;
    int n = idx / RR;
    int r = idx - n * RR;
    int b = n / PP, p = n - b * PP;
    size_t rowp = (size_t)b * PPAD + p;
    float s = bc[r];
    #pragma unroll
    for (int g = 0; g < GS2; ++g)
        s += (float)part[((size_t)g * NROW + rowp) * RP + r];
    out[idx] = s;
}

// ---------------------------------------------------------------------------
extern "C" void kernel_launch(void* const* d_in, const int* in_sizes, int n_in,
                              void* d_out, int out_size, void* d_ws, size_t ws_size,
                              hipStream_t stream) {
    const float* hid  = (const float*)d_in[0];
    const float* att  = (const float*)d_in[1];
    const float* am   = (const float*)d_in[2];
    const int*   head = (const int*)d_in[3];
    const int*   tail = (const int*)d_in[4];
    const float* Wh   = (const float*)d_in[5];
    const float* bh   = (const float*)d_in[6];
    const float* Wt   = (const float*)d_in[7];
    const float* bt   = (const float*)d_in[8];
    const float* Wc   = (const float*)d_in[9];
    const float* bc   = (const float*)d_in[10];
    float* out = (float*)d_out;

    // ---- workspace (~56 MB; part aliases buffers dead before k_logits) ----
    char* w = (char*)d_ws;
    _Float16* Wcp = (_Float16*)w;  w += (size_t)1536 * 512 * 8 * 2;         // 12.58 MB
    _Float16* Vhf = (_Float16*)w;  w += (size_t)BB * 786432 * 2;            //  6.29 MB
    _Float16* Vtf = (_Float16*)w;  w += (size_t)BB * 786432 * 2;
    _Float16* hb2 = (_Float16*)w;  w += (size_t)96 * NROW * 8 * 2;          //  6.29 MB
    _Float16* tb2 = (_Float16*)w;  w += (size_t)96 * NROW * 8 * 2;
    float* Fht      = (float*)w;   w += (size_t)2 * BB * EE * HH * 4;       //  0.79 MB
    float* ent_attn = (float*)w;   w += (size_t)BB * EE * LL * 4;           //  0.52 MB
    char* alias = w;
    _Float16* hidb  = (_Float16*)alias;                                     //  6.29 MB
    _Float16* Whf   = (_Float16*)(alias + 6291456);                         //  1.18 MB
    _Float16* Wtf   = (_Float16*)(alias + 6291456 + 1179648);
    _Float16* pairw = (_Float16*)(alias + 6291456 + 2 * 1179648);           //  8.39 MB
    _Float16* part  = (_Float16*)alias;  // 14.68 MB (16 slices), overlaps
                                         // hidb/Whf/Wtf/pairw-prefix: all
                                         // last-read before k_logits (stream order)

    k_stage0<<<4256, 256, 0, stream>>>(hid, att, head, tail, Wh, bh, Wt, bt, Wc,
                                       hidb, Whf, Wtf, Wcp, ent_attn, Fht);
    k_stage1<<<1024, 256, 0, stream>>>(ent_attn, am, pairw);
    k_vgemm<<<768, 128, 0, stream>>>(hidb, Whf, Wtf, Vhf, Vtf);
    k_proj_mfma<<<768, 128, 0, stream>>>(pairw, Vhf, Vtf, Fht, hb2, tb2);
    k_logits_mfma<<<512, 256, 0, stream>>>(hb2, tb2, Wcp, part);
    k_reduce<<<1504, 256, 0, stream>>>(part, bc, out);
}

// Round 10
// 132.517 us; speedup vs baseline: 1.2619x; 1.2619x over previous
//
#include <hip/hip_runtime.h>
#include <cstdint>
#include <cstddef>

#define BB 4
#define LL 1024
#define HH 768
#define AA 12
#define EE 32
#define PP 992           // EE*(EE-1)
#define PPAD 1024
#define NROW (BB*PPAD)   // 4096
#define NN (BB*PP)       // 3968
#define RR 97
#define RP 112
#define GS2 16           // logits K-slices (K=3072 each)

typedef __attribute__((ext_vector_type(8))) _Float16 half8;
typedef __attribute__((ext_vector_type(4))) _Float16 half4v;
typedef __attribute__((ext_vector_type(2))) _Float16 half2v;
typedef __attribute__((ext_vector_type(4))) float floatx4;

union H8u { half8 v8; half2v v2[4]; };

#define WAITVM(N) asm volatile("s_waitcnt vmcnt(" #N ")" ::: "memory")

__device__ __forceinline__ void gl_lds16(const void* g, void* l) {
    __builtin_amdgcn_global_load_lds(
        (const __attribute__((address_space(1))) unsigned int*)g,
        (__attribute__((address_space(3))) unsigned int*)l, 16, 0, 0);
}

// raw barrier (manual counted vmcnt waits around it; no auto drain)
__device__ __forceinline__ void barrier_raw() {
    asm volatile("" ::: "memory");
    __builtin_amdgcn_s_barrier();
    __builtin_amdgcn_sched_barrier(0);
    asm volatile("" ::: "memory");
}

__device__ __forceinline__ int xswz96(int bid) {  // 768 blocks -> 8 XCD chunks of 96
    return (bid & 7) * 96 + (bid >> 3);
}

__device__ __forceinline__ void pair_decode(int p, int& i0, int& i1) {
    i0 = p / 31;
    int r = p - i0 * 31;
    i1 = r + (r >= i0 ? 1 : 0);
}

__device__ __forceinline__ float fast_tanh(float x) {
    float ax = fabsf(x);
    float t = __builtin_amdgcn_exp2f(ax * -2.885390082f);   // exp(-2|x|)
    float r = (1.f - t) * __builtin_amdgcn_rcpf(1.f + t);
    return copysignf(r, x);
}

// ---------------------------------------------------------------------------
// stage0 (merged independent sections):
//  [0,1536)    Wc repack via LDS (coalesced): one 32-row k-step per block
//  [1536,2112) Wh2/Wt2 (rows 768..1535) -> frag layout
//  [2112,3648) hid f32 -> f16 row-major
//  [3648,4160) ent_attn gather (be, quarter)
//  [4160,4736) Wh1/Wt1 (rows 0..767) -> frag layout (for MFMA Fht)
// ---------------------------------------------------------------------------
__global__ __launch_bounds__(256) void k_stage0(
        const float* __restrict__ hid, const float* __restrict__ att,
        const int* __restrict__ head, const int* __restrict__ tail,
        const float* __restrict__ Wh, const float* __restrict__ Wt,
        const float* __restrict__ Wc,
        _Float16* __restrict__ hidb, _Float16* __restrict__ Whf,
        _Float16* __restrict__ Wtf, _Float16* __restrict__ W1hf,
        _Float16* __restrict__ W1tf, _Float16* __restrict__ Wcp,
        float* __restrict__ ent_attn) {
    __shared__ float ldw[32][101];   // Wc staging (pad 101 spreads banks)
    int bid = blockIdx.x, tid = threadIdx.x;
    if (bid < 1536) {
        int ksg = bid;
        int w = tid >> 6, lane = tid & 63;
        const float* src = Wc + (size_t)ksg * 32 * RR;
        #pragma unroll
        for (int rr = 0; rr < 8; ++rr) {
            int row = w * 8 + rr;
            ldw[row][lane] = src[(size_t)row * RR + lane];
            if (lane < 33) ldw[row][64 + lane] = src[(size_t)row * RR + 64 + lane];
        }
        __syncthreads();
        #pragma unroll
        for (int j = 0; j < 2; ++j) {
            int f = tid + j * 256;
            int rt = f >> 6, lf = f & 63;
            int c = rt * 16 + (lf & 15);
            int kb = (lf >> 4) * 8;
            _Float16 v[8];
            #pragma unroll
            for (int e = 0; e < 8; ++e)
                v[e] = (c < RR) ? (_Float16)ldw[kb + e][c] : (_Float16)0.f;
            *(half8*)(Wcp + ((size_t)ksg * 512 + f) * 8) = *(const half8*)v;
        }
    } else if (bid < 2112) {
        int which = (bid < 1824) ? 0 : 1;
        const float* src = (which ? Wt : Wh) + (size_t)HH * HH;
        _Float16* dst = which ? Wtf : Whf;
        int idx = (bid - (which ? 1824 : 1536)) * 256 + tid;   // 73728 = 24*48*64
        int lane = idx & 63, f = idx >> 6;
        int ct = f % 48, ks = f / 48;
        int c = ct * 16 + (lane & 15);
        int kb = ks * 32 + (lane >> 4) * 8;
        _Float16 v[8];
        #pragma unroll
        for (int e = 0; e < 8; ++e)
            v[e] = (_Float16)src[(size_t)(kb + e) * HH + c];
        *(half8*)(dst + (size_t)idx * 8) = *(const half8*)v;
    } else if (bid < 3648) {
        int idx = (bid - 2112) * 256 + tid;
        const float* s = hid + (size_t)idx * 8;
        float4 a = *(const float4*)s;
        float4 b = *(const float4*)(s + 4);
        half8 v = { (_Float16)a.x, (_Float16)a.y, (_Float16)a.z, (_Float16)a.w,
                    (_Float16)b.x, (_Float16)b.y, (_Float16)b.z, (_Float16)b.w };
        *(half8*)(hidb + (size_t)idx * 8) = v;
    } else if (bid < 4160) {
        int q = bid - 3648;                    // 512: (be, quarter)
        int be = q >> 2, qt = q & 3;
        int b = be >> 5;
        int hd = head[be], tl = tail[be];
        const float* abase = att + (size_t)b * AA * LL * LL;
        int ll = qt * 256 + tid;
        float s = 0.f;
        #pragma unroll
        for (int a = 0; a < AA; ++a) {
            const float* ar = abase + (size_t)a * LL * LL;
            s += ar[(size_t)hd * LL + ll] + ar[(size_t)tl * LL + ll];
        }
        ent_attn[(size_t)be * LL + ll] = s * (0.5f / AA);
    } else {
        int which = (bid < 4448) ? 0 : 1;
        const float* src = which ? Wt : Wh;    // rows 0..767 = W1 half
        _Float16* dst = which ? W1tf : W1hf;
        int idx = (bid - (which ? 4448 : 4160)) * 256 + tid;
        int lane = idx & 63, f = idx >> 6;
        int ct = f % 48, ks = f / 48;
        int c = ct * 16 + (lane & 15);
        int kb = ks * 32 + (lane >> 4) * 8;
        _Float16 v[8];
        #pragma unroll
        for (int e = 0; e < 8; ++e)
            v[e] = (_Float16)src[(size_t)(kb + e) * HH + c];
        *(half8*)(dst + (size_t)idx * 8) = *(const half8*)v;
    }
}

// ---------------------------------------------------------------------------
// stage1:
//  [0,1024)    pairw: ONE WAVE PER ROW, no LDS/barriers (4 rows/block)
//  [1024,1120) Fht MFMA: Fht[mat,b,e,:] = (0.5*(hidb[hd]+hidb[tl])) @ W1 + b
//              barrier-free, A gathered in-register, B from W1 fragments.
// ---------------------------------------------------------------------------
__global__ __launch_bounds__(256) void k_stage1(
        const float* __restrict__ ent_attn, const float* __restrict__ am,
        const int* __restrict__ head, const int* __restrict__ tail,
        const _Float16* __restrict__ hidb,
        const _Float16* __restrict__ W1hf, const _Float16* __restrict__ W1tf,
        const float* __restrict__ bh, const float* __restrict__ bt,
        _Float16* __restrict__ pairw, float* __restrict__ Fht) {
    int tid = threadIdx.x;
    if (blockIdx.x < 1024) {
        int lane = tid & 63, w = tid >> 6;
        int prow = blockIdx.x * 4 + w;
        int b = prow >> 10, p = prow & 1023;
        _Float16* dst = pairw + (size_t)prow * LL;
        if (p >= PP) {
            #pragma unroll
            for (int c = 0; c < 4; ++c) {
                half4v z = {};
                *(half4v*)(dst + c * 256 + lane * 4) = z;
            }
            return;
        }
        int i0, i1; pair_decode(p, i0, i1);
        const float* e0  = ent_attn + ((size_t)b * EE + i0) * LL;
        const float* e1  = ent_attn + ((size_t)b * EE + i1) * LL;
        const float* amr = am + (size_t)b * LL;
        float wv[16];
        float s = 0.f;
        #pragma unroll
        for (int c = 0; c < 4; ++c) {
            int o = c * 256 + lane * 4;
            float4 a = *(const float4*)(e0 + o);
            float4 d = *(const float4*)(e1 + o);
            float4 m = *(const float4*)(amr + o);
            wv[c*4+0] = a.x * d.x * m.x; wv[c*4+1] = a.y * d.y * m.y;
            wv[c*4+2] = a.z * d.z * m.z; wv[c*4+3] = a.w * d.w * m.w;
            s += wv[c*4+0] + wv[c*4+1] + wv[c*4+2] + wv[c*4+3];
        }
        #pragma unroll
        for (int off = 32; off > 0; off >>= 1) s += __shfl_down(s, off, 64);
        float tot = __shfl(s, 0, 64);
        float inv = 1.0f / (tot + 1e-20f);
        #pragma unroll
        for (int c = 0; c < 4; ++c) {
            half4v o4 = { (_Float16)(wv[c*4+0] * inv), (_Float16)(wv[c*4+1] * inv),
                          (_Float16)(wv[c*4+2] * inv), (_Float16)(wv[c*4+3] * inv) };
            *(half4v*)(dst + c * 256 + lane * 4) = o4;
        }
    } else {
        int q = blockIdx.x - 1024;             // 96: (mat,b,ct)
        int ct = q % 12, b = (q / 12) % BB, mat = q / 48;
        const _Float16* Wf = mat ? W1tf : W1hf;
        const float* bias = mat ? bt : bh;
        int lane = tid & 63, w = tid >> 6;     // 4 waves
        int row = (w & 1) * 16 + (lane & 15);
        int k8 = (lane >> 4) * 8;
        int hd = head[b * EE + row], tl = tail[b * EE + row];
        const _Float16* Ah = hidb + ((size_t)b * LL + hd) * HH + k8;
        const _Float16* At = hidb + ((size_t)b * LL + tl) * HH + k8;
        int ctG0 = ct * 4 + (w >> 1) * 2;      // 2 col-tiles per wave
        const half8* B0 = (const half8*)Wf + (size_t)ctG0 * 64 + lane;
        floatx4 acc[2] = {};
        half2v hlf = { (_Float16)0.5f, (_Float16)0.5f };
        for (int ks = 0; ks < 24; ++ks) {
            H8u a_, b_, av;
            a_.v8 = *(const half8*)(Ah + ks * 32);
            b_.v8 = *(const half8*)(At + ks * 32);
            #pragma unroll
            for (int qq = 0; qq < 4; ++qq) av.v2[qq] = (a_.v2[qq] + b_.v2[qq]) * hlf;
            const half8* Bk = B0 + (size_t)ks * 48 * 64;
            acc[0] = __builtin_amdgcn_mfma_f32_16x16x32_f16(av.v8, Bk[0], acc[0], 0, 0, 0);
            acc[1] = __builtin_amdgcn_mfma_f32_16x16x32_f16(av.v8, Bk[64], acc[1], 0, 0, 0);
        }
        int rb = lane & 15, u = lane >> 4;
        #pragma unroll
        for (int cc = 0; cc < 2; ++cc) {
            int c = (ctG0 + cc) * 16 + rb;
            float bi = bias[c];
            float* dst = Fht + (((size_t)mat * BB + b) * EE + (w & 1) * 16 + u * 4) * HH + c;
            #pragma unroll
            for (int qq = 0; qq < 4; ++qq)
                dst[(size_t)qq * HH] = acc[cc][qq] + bi;
        }
    }
}

// ---------------------------------------------------------------------------
// vgemm: Vh = hidb@Wh2, Vt = hidb@Wt2 (r8 proven: depth-2, 4-buffer,
// one barrier/step). Output scattered into proj-B fragment layout.
// ---------------------------------------------------------------------------
__global__ __launch_bounds__(128) void k_vgemm(
        const _Float16* __restrict__ hidb,
        const _Float16* __restrict__ Whf, const _Float16* __restrict__ Wtf,
        _Float16* __restrict__ Vhf, _Float16* __restrict__ Vtf) {
    int bid = xswz96(blockIdx.x);
    int cb = bid >> 6, mI = bid & 63;
    int ct0 = cb * 4;
    __shared__ __align__(16) _Float16 Bs[4][4096];
    int tid = threadIdx.x, lane = tid & 63, wid = tid >> 6;
    int r0 = wid * 32 + (lane & 15);
    int kg8 = (lane >> 4) * 8;

    const _Float16* A0 = hidb + (size_t)(mI * 64 + r0) * HH + kg8;
    const _Float16* A1 = A0 + 16 * HH;
    const char* WhB = (const char*)Whf + (size_t)ct0 * 1024;
    const char* WtB = (const char*)Wtf + (size_t)ct0 * 1024;
    char* LB = (char*)&Bs[0][0];
    int lo = wid * 2048 + lane * 16;
    int ld = wid * 2048;

    #pragma unroll
    for (int j = 0; j < 2; ++j) {
        gl_lds16(WhB + j * 1024 + lo, LB + j * 1024 + ld);
        gl_lds16(WtB + j * 1024 + lo, LB + 4096 + j * 1024 + ld);
    }
    half8 a0c = *(const half8*)A0;
    half8 a1c = *(const half8*)A1;
    {
        const char* hs = WhB + 49152;   // step 1: +48*1024
        const char* ts = WtB + 49152;
        #pragma unroll
        for (int j = 0; j < 2; ++j) {
            gl_lds16(hs + j * 1024 + lo, LB + 8192 + j * 1024 + ld);
            gl_lds16(ts + j * 1024 + lo, LB + 8192 + 4096 + j * 1024 + ld);
        }
    }
    floatx4 aH[2][4] = {}, aT[2][4] = {};
    half8 a0n = a0c, a1n = a1c;
    for (int ks = 0; ks < 24; ++ks) {
        int buf = ks & 3;
        if (ks < 23) {
            a0n = *(const half8*)(A0 + (ks + 1) * 32);
            a1n = *(const half8*)(A1 + (ks + 1) * 32);
        }
        if (ks < 22) {
            const char* hs = WhB + (size_t)(ks + 2) * 49152;
            const char* ts = WtB + (size_t)(ks + 2) * 49152;
            char* lb = LB + ((ks + 2) & 3) * 8192;
            #pragma unroll
            for (int j = 0; j < 2; ++j) {
                gl_lds16(hs + j * 1024 + lo, lb + j * 1024 + ld);
                gl_lds16(ts + j * 1024 + lo, lb + 4096 + j * 1024 + ld);
            }
            WAITVM(12);
        } else if (ks == 22) { WAITVM(8); } else { WAITVM(2); }
        barrier_raw();
        const half8* bp = (const half8*)(LB + buf * 8192) + lane;
        __builtin_amdgcn_s_setprio(1);
        #pragma unroll
        for (int ct = 0; ct < 4; ++ct) {
            half8 bvh = bp[ct * 64];
            half8 bvt = bp[256 + ct * 64];
            aH[0][ct] = __builtin_amdgcn_mfma_f32_16x16x32_f16(a0c, bvh, aH[0][ct], 0, 0, 0);
            aH[1][ct] = __builtin_amdgcn_mfma_f32_16x16x32_f16(a1c, bvh, aH[1][ct], 0, 0, 0);
            aT[0][ct] = __builtin_amdgcn_mfma_f32_16x16x32_f16(a0c, bvt, aT[0][ct], 0, 0, 0);
            aT[1][ct] = __builtin_amdgcn_mfma_f32_16x16x32_f16(a1c, bvt, aT[1][ct], 0, 0, 0);
        }
        __builtin_amdgcn_s_setprio(0);
        a0c = a0n; a1c = a1n;
    }
    int b = mI >> 4;
    int kspB = (mI & 15) * 2 + wid;
    int u = lane >> 4, rb = lane & 15;
    int estart = (u & 1) * 4;
    size_t bofs = (size_t)b * 786432;
    #pragma unroll
    for (int rs = 0; rs < 2; ++rs) {
        int laneL = (rs * 2 + (u >> 1)) * 16 + rb;
        #pragma unroll
        for (int ct = 0; ct < 4; ++ct) {
            size_t base = bofs + ((size_t)(kspB * 48 + ct0 + ct) * 64 + laneL) * 8 + estart;
            half4v hv = { (_Float16)aH[rs][ct][0], (_Float16)aH[rs][ct][1],
                          (_Float16)aH[rs][ct][2], (_Float16)aH[rs][ct][3] };
            half4v tv = { (_Float16)aT[rs][ct][0], (_Float16)aT[rs][ct][1],
                          (_Float16)aT[rs][ct][2], (_Float16)aT[rs][ct][3] };
            *(half4v*)(Vhf + base) = hv;
            *(half4v*)(Vtf + base) = tv;
        }
    }
}

// ---------------------------------------------------------------------------
// proj: h = tanh(Fh[i0] + pairw@Vh), t = tanh(Ft[i1] + pairw@Vt)  (r8 version)
// ---------------------------------------------------------------------------
__global__ __launch_bounds__(128) void k_proj_mfma(
        const _Float16* __restrict__ pairw,
        const _Float16* __restrict__ Vhf, const _Float16* __restrict__ Vtf,
        const float* __restrict__ Fht,
        _Float16* __restrict__ hb, _Float16* __restrict__ tb) {
    int bid = xswz96(blockIdx.x);
    int bc = bid >> 4, mI = bid & 15;       // bc = b*12+cb
    int b = bc / 12, cb = bc - b * 12;
    int ct0 = cb * 4;
    __shared__ __align__(16) _Float16 Bs[4][4096];
    int tid = threadIdx.x, lane = tid & 63, wid = tid >> 6;
    int r0 = wid * 32 + (lane & 15);
    int kg8 = (lane >> 4) * 8;

    const _Float16* A0 = pairw + (size_t)(b * PPAD + mI * 64 + r0) * LL + kg8;
    const _Float16* A1 = A0 + 16 * LL;
    const char* VhB = (const char*)(Vhf + (size_t)b * 786432) + (size_t)ct0 * 1024;
    const char* VtB = (const char*)(Vtf + (size_t)b * 786432) + (size_t)ct0 * 1024;
    char* LB = (char*)&Bs[0][0];
    int lo = wid * 2048 + lane * 16;
    int ld = wid * 2048;

    #pragma unroll
    for (int j = 0; j < 2; ++j) {
        gl_lds16(VhB + j * 1024 + lo, LB + j * 1024 + ld);
        gl_lds16(VtB + j * 1024 + lo, LB + 4096 + j * 1024 + ld);
    }
    half8 a0c = *(const half8*)A0;
    half8 a1c = *(const half8*)A1;
    {
        const char* hs = VhB + 49152;
        const char* ts = VtB + 49152;
        #pragma unroll
        for (int j = 0; j < 2; ++j) {
            gl_lds16(hs + j * 1024 + lo, LB + 8192 + j * 1024 + ld);
            gl_lds16(ts + j * 1024 + lo, LB + 8192 + 4096 + j * 1024 + ld);
        }
    }
    floatx4 aH[2][4] = {}, aT4[2][4] = {};
    half8 a0n = a0c, a1n = a1c;
    for (int ks = 0; ks < 32; ++ks) {
        int buf = ks & 3;
        if (ks < 31) {
            a0n = *(const half8*)(A0 + (ks + 1) * 32);
            a1n = *(const half8*)(A1 + (ks + 1) * 32);
        }
        if (ks < 30) {
            const char* hs = VhB + (size_t)(ks + 2) * 49152;
            const char* ts = VtB + (size_t)(ks + 2) * 49152;
            char* lb = LB + ((ks + 2) & 3) * 8192;
            #pragma unroll
            for (int j = 0; j < 2; ++j) {
                gl_lds16(hs + j * 1024 + lo, lb + j * 1024 + ld);
                gl_lds16(ts + j * 1024 + lo, lb + 4096 + j * 1024 + ld);
            }
            WAITVM(12);
        } else if (ks == 30) { WAITVM(8); } else { WAITVM(2); }
        barrier_raw();
        const half8* bp = (const half8*)(LB + buf * 8192) + lane;
        __builtin_amdgcn_s_setprio(1);
        #pragma unroll
        for (int ct = 0; ct < 4; ++ct) {
            half8 bvh = bp[ct * 64];
            half8 bvt = bp[256 + ct * 64];
            aH[0][ct]  = __builtin_amdgcn_mfma_f32_16x16x32_f16(a0c, bvh, aH[0][ct], 0, 0, 0);
            aH[1][ct]  = __builtin_amdgcn_mfma_f32_16x16x32_f16(a1c, bvh, aH[1][ct], 0, 0, 0);
            aT4[0][ct] = __builtin_amdgcn_mfma_f32_16x16x32_f16(a0c, bvt, aT4[0][ct], 0, 0, 0);
            aT4[1][ct] = __builtin_amdgcn_mfma_f32_16x16x32_f16(a1c, bvt, aT4[1][ct], 0, 0, 0);
        }
        __builtin_amdgcn_s_setprio(0);
        a0c = a0n; a1c = a1n;
    }
    const float* FhB = Fht + (size_t)b * EE * HH;
    const float* FtB = Fht + (size_t)(BB + b) * EE * HH;
    int u = lane >> 4, rb = lane & 15;
    #pragma unroll
    for (int rs = 0; rs < 2; ++rs) {
        int pb = mI * 64 + wid * 32 + rs * 16 + u * 4;
        int i0a[4], i1a[4];
        #pragma unroll
        for (int q = 0; q < 4; ++q) {
            int p = pb + q;
            if (p < PP) pair_decode(p, i0a[q], i1a[q]);
            else { i0a[q] = -1; i1a[q] = -1; }
        }
        #pragma unroll
        for (int ct = 0; ct < 4; ++ct) {
            int c = (ct0 + ct) * 16 + rb;
            #pragma unroll
            for (int q = 0; q < 4; ++q) {
                size_t row = (size_t)b * PPAD + pb + q;
                _Float16 hv = (_Float16)0.f, tv = (_Float16)0.f;
                if (i0a[q] >= 0) {
                    hv = (_Float16)fast_tanh(aH[rs][ct][q]  + FhB[(size_t)i0a[q] * HH + c]);
                    tv = (_Float16)fast_tanh(aT4[rs][ct][q] + FtB[(size_t)i1a[q] * HH + c]);
                }
                hb[row * HH + c] = hv;
                tb[row * HH + c] = tv;
            }
        }
    }
}

// ---------------------------------------------------------------------------
// logits: 512 blocks = 2/CU, 4 waves x 32 rows, 16 K-slices of 3072 (r8).
// ---------------------------------------------------------------------------
__global__ __launch_bounds__(256) void k_logits_mfma(
        const _Float16* __restrict__ hb, const _Float16* __restrict__ tb,
        const _Float16* __restrict__ Wcp, _Float16* __restrict__ part) {
    int bid = blockIdx.x;
    int gs = (bid & 7) * 2 + ((bid >> 3) & 1);   // K-slice 0..15
    int nb = bid >> 4;                            // row-tile 0..31
    int n0 = nb * 128;
    int hcol0 = gs * 48;
    int g0 = (3 * gs) >> 2;                       // first g touched
    int tcol0 = g0 * 64;
    __shared__ __align__(16) _Float16 hT[6][128][8];    // 12 KB
    __shared__ __align__(16) _Float16 tT[16][128][8];   // 32 KB
    __shared__ __align__(16) _Float16 Bs[4][4096];      // 32 KB
    int tid = threadIdx.x, lane = tid & 63, wid = tid >> 6;

    #pragma unroll
    for (int it = 0; it < 3; ++it) {
        int idx = tid + it * 256;      // 768 = 6*128
        int ch = idx >> 7, row = idx & 127;
        *(half8*)&hT[ch][row][0] =
            *(const half8*)(hb + (size_t)(n0 + row) * HH + hcol0 + ch * 8);
    }
    int nch = (HH - tcol0) >> 3;       // guard K-edge (slice 15: 8 chunks)
    #pragma unroll
    for (int it = 0; it < 8; ++it) {
        int idx = tid + it * 256;      // 2048 = 16*128
        int ch = idx >> 7, row = idx & 127;
        if (ch < nch)
            *(half8*)&tT[ch][row][0] =
                *(const half8*)(tb + (size_t)(n0 + row) * HH + tcol0 + ch * 8);
    }
    __syncthreads();

    const char* WcB = (const char*)Wcp + (size_t)gs * 96 * 8192;
    char* LB = (char*)&Bs[0][0];
    int lo = wid * 2048 + lane * 16;
    int ld = wid * 2048;
    #pragma unroll
    for (int s = 0; s < 2; ++s) {
        const char* sp = WcB + (size_t)s * 8192;
        char* lb = LB + s * 8192;
        gl_lds16(sp + lo, lb + ld);
        gl_lds16(sp + 1024 + lo, lb + 1024 + ld);
    }
    int r0 = wid * 32 + (lane & 15);
    int kgrp = lane >> 4;
    floatx4 acc[2][7] = {};

    for (int ks = 0; ks < 96; ++ks) {
        int buf = ks & 3;
        int ksg = gs * 96 + ks;
        int g = ksg >> 7;
        int kin = ksg & 127;
        int i = kin >> 1, jh = kin & 1;
        int hloc = g * 64 + i - hcol0;                    // in [0,48)
        int chT = ((g * 64 + jh * 32 - tcol0) >> 3) + kgrp;
        _Float16 h0 = hT[hloc >> 3][r0][hloc & 7];
        _Float16 h1 = hT[hloc >> 3][r0 + 16][hloc & 7];
        H8u t0u, t1u, a0, a1;
        t0u.v8 = *(const half8*)&tT[chT][r0][0];
        t1u.v8 = *(const half8*)&tT[chT][r0 + 16][0];
        half2v h02 = { h0, h0 }, h12 = { h1, h1 };
        #pragma unroll
        for (int q = 0; q < 4; ++q) {
            a0.v2[q] = h02 * t0u.v2[q];
            a1.v2[q] = h12 * t1u.v2[q];
        }
        if (ks < 94) {
            const char* sp = WcB + (size_t)(ks + 2) * 8192;
            char* lb = LB + ((ks + 2) & 3) * 8192;
            gl_lds16(sp + lo, lb + ld);
            gl_lds16(sp + 1024 + lo, lb + 1024 + ld);
            WAITVM(4);
        } else if (ks == 94) { WAITVM(2); } else { WAITVM(0); }
        barrier_raw();
        const half8* bp = (const half8*)(LB + buf * 8192) + lane;
        __builtin_amdgcn_s_setprio(1);
        #pragma unroll
        for (int rt = 0; rt < 7; ++rt) {
            half8 bv = bp[rt * 64];
            acc[0][rt] = __builtin_amdgcn_mfma_f32_16x16x32_f16(a0.v8, bv, acc[0][rt], 0, 0, 0);
            acc[1][rt] = __builtin_amdgcn_mfma_f32_16x16x32_f16(a1.v8, bv, acc[1][rt], 0, 0, 0);
        }
        __builtin_amdgcn_s_setprio(0);
    }
    int rb = lane & 15, u = lane >> 4;
    #pragma unroll
    for (int rs = 0; rs < 2; ++rs) {
        int nbase = n0 + wid * 32 + rs * 16 + u * 4;
        #pragma unroll
        for (int rt = 0; rt < 7; ++rt)
            #pragma unroll
            for (int q = 0; q < 4; ++q)
                part[((size_t)gs * NROW + nbase + q) * RP + rt * 16 + rb] =
                    (_Float16)acc[rs][rt][q];
    }
}

// ---------------------------------------------------------------------------
// reduce: logits[n,r] = bc[r] + sum_gs part[gs, rowp(n), r]
// ---------------------------------------------------------------------------
__global__ __launch_bounds__(256) void k_reduce(
        const _Float16* __restrict__ part, const float* __restrict__ bc,
        float* __restrict__ out) {
    int idx = blockIdx.x * 256 + threadIdx.x;
    if (idx >= NN * RR) return;
    int n = idx / RR;
    int r = idx - n * RR;
    int b = n / PP, p = n - b * PP;
    size_t rowp = (size_t)b * PPAD + p;
    float s = bc[r];
    #pragma unroll
    for (int g = 0; g < GS2; ++g)
        s += (float)part[((size_t)g * NROW + rowp) * RP + r];
    out[idx] = s;
}

// ---------------------------------------------------------------------------
extern "C" void kernel_launch(void* const* d_in, const int* in_sizes, int n_in,
                              void* d_out, int out_size, void* d_ws, size_t ws_size,
                              hipStream_t stream) {
    const float* hid  = (const float*)d_in[0];
    const float* att  = (const float*)d_in[1];
    const float* am   = (const float*)d_in[2];
    const int*   head = (const int*)d_in[3];
    const int*   tail = (const int*)d_in[4];
    const float* Wh   = (const float*)d_in[5];
    const float* bh   = (const float*)d_in[6];
    const float* Wt   = (const float*)d_in[7];
    const float* bt   = (const float*)d_in[8];
    const float* Wc   = (const float*)d_in[9];
    const float* bc   = (const float*)d_in[10];
    float* out = (float*)d_out;

    // ---- workspace (~58 MB; part aliases buffers dead before k_logits) ----
    char* w = (char*)d_ws;
    _Float16* Wcp = (_Float16*)w;  w += (size_t)1536 * 512 * 8 * 2;         // 12.58 MB
    _Float16* Vhf = (_Float16*)w;  w += (size_t)BB * 786432 * 2;            //  6.29 MB
    _Float16* Vtf = (_Float16*)w;  w += (size_t)BB * 786432 * 2;
    _Float16* hbv = (_Float16*)w;  w += (size_t)NROW * HH * 2;              //  6.29 MB
    _Float16* tbv = (_Float16*)w;  w += (size_t)NROW * HH * 2;
    float* Fht      = (float*)w;   w += (size_t)2 * BB * EE * HH * 4;       //  0.79 MB
    float* ent_attn = (float*)w;   w += (size_t)BB * EE * LL * 4;           //  0.52 MB
    char* alias = w;
    _Float16* hidb  = (_Float16*)alias;                                     //  6.29 MB
    _Float16* Whf   = (_Float16*)(alias + 6291456);                         //  1.18 MB
    _Float16* Wtf   = (_Float16*)(alias + 6291456 + 1179648);
    _Float16* pairw = (_Float16*)(alias + 6291456 + 2 * 1179648);           //  8.39 MB
    _Float16* W1hf  = (_Float16*)(alias + 6291456 + 2 * 1179648 + 8388608); //  1.18 MB
    _Float16* W1tf  = (_Float16*)(alias + 6291456 + 3 * 1179648 + 8388608);
    _Float16* part  = (_Float16*)alias;  // 14.68 MB (16 slices): overlaps
                                         // hidb/Whf/Wtf/pairw-prefix only; all
                                         // last-read before k_logits (stream order)

    k_stage0<<<4736, 256, 0, stream>>>(hid, att, head, tail, Wh, Wt, Wc,
                                       hidb, Whf, Wtf, W1hf, W1tf, Wcp, ent_attn);
    k_stage1<<<1120, 256, 0, stream>>>(ent_attn, am, head, tail, hidb,
                                       W1hf, W1tf, bh, bt, pairw, Fht);
    k_vgemm<<<768, 128, 0, stream>>>(hidb, Whf, Wtf, Vhf, Vtf);
    k_proj_mfma<<<768, 128, 0, stream>>>(pairw, Vhf, Vtf, Fht, hbv, tbv);
    k_logits_mfma<<<512, 256, 0, stream>>>(hbv, tbv, Wcp, part);
    k_reduce<<<1504, 256, 0, stream>>>(part, bc, out);
}